// Round 1
// 303.132 us; speedup vs baseline: 1.0566x; 1.0566x over previous
//
#include <hip/hip_runtime.h>

typedef __bf16 bf16x8 __attribute__((ext_vector_type(8)));
typedef float f32x4 __attribute__((ext_vector_type(4)));

__device__ __forceinline__ unsigned short f2b(float f) {
    union { float f; unsigned u; } c; c.f = f;
    unsigned u = c.u;
    return (unsigned short)((u + 0x7FFFu + ((u >> 16) & 1u)) >> 16);
}

__device__ __forceinline__ unsigned pack2(float v0, float v1) {
    union { __bf16 h[2]; unsigned u; } c;
    c.h[0] = (__bf16)v0; c.h[1] = (__bf16)v1;
    return c.u;
}

// Build layer-0 B-frags: B0[t][s] holds |x_i - x_j| transposed (k=fin, col=pos).
// Lane (cl,g): elem e = h0[pos=16t+cl][f=32s+8g+e]; frags fully valid or fully zero
// (CIN multiple of 8).
template<int CIN, int KN0>
__device__ __forceinline__ void build_frags0(const float* __restrict__ xi,
    const float* __restrict__ xj, int cl, int g, bf16x8 (&B0)[2][6])
{
#pragma unroll
    for (int s = 0; s < KN0; ++s) {
        const int f0 = s * 32 + 8 * g;
        const bool valid = f0 < CIN;
        f32x4 xa = {0.f,0.f,0.f,0.f}, xb = {0.f,0.f,0.f,0.f};
        if (valid) { xa = *(const f32x4*)(xi + f0); xb = *(const f32x4*)(xi + f0 + 4); }
#pragma unroll
        for (int t = 0; t < 2; ++t) {
            bf16x8 r;
            if (valid) {
                const float* pj = xj + (16 * t + cl) * CIN + f0;
                f32x4 ja = *(const f32x4*)pj, jb = *(const f32x4*)(pj + 4);
#pragma unroll
                for (int e = 0; e < 4; ++e) {
                    r[e]     = (__bf16)fabsf(xa[e] - ja[e]);
                    r[e + 4] = (__bf16)fabsf(xb[e] - jb[e]);
                }
            } else {
#pragma unroll
                for (int e = 0; e < 8; ++e) r[e] = (__bf16)0.f;
            }
            B0[t][s] = r;
        }
    }
}

// One F-mode layer: D'(c,t) = Wc^T · Xc^T (+bias, leaky).
// Shuffle-free repack: next-layer frag s takes channels from acc tiles a=2s,2s+1
// which live in the SAME lane (D-layout: lane (cl,g) holds ch 16a+4g+r, pos=cl).
// Downstream weights are packed with matching k-permutation
//   tau(s,g,e) = 32s + 16*(e>>2) + 4g + (e&3)
// so the MFMA dot product pairs correctly without any cross-lane movement.
template<int KN, int CB>
__device__ __forceinline__ void run_layer(const unsigned short* __restrict__ wp,
    const float* __restrict__ bias, const bf16x8 (&Bc)[2][6], bf16x8 (&Bn)[2][6],
    int lane, int g)
{
#pragma unroll
    for (int cp = 0; cp < CB / 2; ++cp) {
        f32x4 acc[2][2];                       // [cc][t]
#pragma unroll
        for (int cc = 0; cc < 2; ++cc) {
            f32x4 bv = *(const f32x4*)&bias[(2 * cp + cc) * 16 + 4 * g];
            acc[cc][0] = bv; acc[cc][1] = bv;
        }
#pragma unroll
        for (int s = 0; s < KN; ++s) {
#pragma unroll
            for (int cc = 0; cc < 2; ++cc) {
                bf16x8 w = *(const bf16x8*)(wp + (((2 * cp + cc) * KN + s) * 64 + lane) * 8);
#pragma unroll
                for (int t = 0; t < 2; ++t)
                    acc[cc][t] = __builtin_amdgcn_mfma_f32_16x16x32_bf16(w, Bc[t][s], acc[cc][t], 0, 0, 0);
            }
        }
#pragma unroll
        for (int t = 0; t < 2; ++t) {
            union { unsigned w[4]; bf16x8 v; } outv;
#pragma unroll
            for (int cc = 0; cc < 2; ++cc)
#pragma unroll
                for (int m = 0; m < 2; ++m) {
                    float v0 = acc[cc][t][2 * m], v1 = acc[cc][t][2 * m + 1];
                    v0 = fmaxf(v0, 0.01f * v0);      // LeakyReLU(0.01)
                    v1 = fmaxf(v1, 0.01f * v1);
                    outv.w[cc * 2 + m] = pack2(v0, v1);
                }
            Bn[t][cp] = outv.v;
        }
    }
}

// Fused adjacency MLP, F-mode, zero LDS, zero barriers, zero shuffles.
// Block = 256 threads = 4 waves; wave owns 32 positions (fixed b,i; 32 j's).
template<int CIN, int KN0>
__global__ __launch_bounds__(256, 3)
void adj_mlp_kernel(const float* __restrict__ src,
                    const unsigned short* __restrict__ wchain,
                    const unsigned short* __restrict__ w4f,
                    const float* __restrict__ b0, const float* __restrict__ b1,
                    const float* __restrict__ b2, const float* __restrict__ b3,
                    const float* __restrict__ b4,
                    float* __restrict__ logits)
{
    const int tid = threadIdx.x;
    const int wid = tid >> 6, lane = tid & 63;
    const int cl = lane & 15, g = lane >> 4;
    const int p0 = blockIdx.x * 128 + wid * 32;
    const int b = p0 >> 16, i = (p0 >> 8) & 255, j0 = p0 & 255;
    const float* xi = src + (b * 256 + i) * CIN;
    const float* xj = src + (b * 256 + j0) * CIN;

    bf16x8 Ba[2][6], Bb[2][6];
    build_frags0<CIN, KN0>(xi, xj, cl, g, Ba);

    const unsigned short* wp = wchain;
    run_layer<KN0, 12>(wp, b0, Ba, Bb, lane, g); wp += 12 * KN0 * 512;
    run_layer<6, 12>(wp, b1, Bb, Ba, lane, g);   wp += 36864;
    run_layer<6, 12>(wp, b2, Ba, Bb, lane, g);   wp += 36864;
    run_layer<6, 6>(wp, b3, Bb, Ba, lane, g);    // 192 -> 96, frags in Ba[t][0..2]

    // final 96 -> 1: A = w4 (row 0), D row0/col=pos -> lanes g==0, reg 0
    const float bv4 = b4[0];
#pragma unroll
    for (int t = 0; t < 2; ++t) {
        f32x4 acc = {bv4, bv4, bv4, bv4};
#pragma unroll
        for (int s = 0; s < 3; ++s) {
            bf16x8 w = *(const bf16x8*)(w4f + (s * 64 + lane) * 8);
            acc = __builtin_amdgcn_mfma_f32_16x16x32_bf16(w, Ba[t][s], acc, 0, 0, 0);
        }
        if (g == 0) {
            int j = j0 + 16 * t + cl;
            float lg = acc[0];
            if (j == i) lg -= 1e8f;
            logits[(b * 256 + i) * 256 + j] = lg;
        }
    }
}

// Pre-pack weight matrices (bf16). Same lane<->element map serves A- and B-frags.
// Layers 0-7: conv chains (a0 then a1). Layers 8-9: w4 vectors in row/col 0.
// Layers whose INPUT comes from a previous MFMA layer (1,2,3, 5,6,7, 8,9) use the
// shuffle-free k-permutation tau(s,g,e) = 32s + 16*(e>>2) + 4g + (e&3); layers fed
// by build_frags0 (0, 4) keep the natural order k = 32s + 8g + e.
struct PackPtrs { const float* w[10]; };

__global__ void pack_kernel(PackPtrs pp, unsigned short* __restrict__ dst)
{
    const int K_[10]   = {24, 192, 192, 192, 72, 192, 192, 192, 96, 96};
    const int KN_[10]  = {1, 6, 6, 6, 3, 6, 6, 6, 3, 3};
    const int NO_[10]  = {192, 192, 192, 96, 192, 192, 192, 96, 1, 1};
    const int OFF_[10] = {0, 6144, 43008, 79872, 98304, 116736, 153600, 190464, 208896, 210432};
    const int LEN_[10] = {6144, 36864, 36864, 18432, 18432, 36864, 36864, 18432, 1536, 1536};
    int t = blockIdx.x * 256 + threadIdx.x;   // total threads == 211968 exactly
    int layer = 0, base = 0;
#pragma unroll
    for (int L = 0; L < 10; ++L)
        if (t >= base + LEN_[L]) { base += LEN_[L]; layer = L + 1; }
    if (layer >= 10) return;
    int u = t - base;
    int e = u & 7;
    int lane = (u >> 3) & 63;
    int gg = lane >> 4;
    int KN = KN_[layer];
    int fi = u >> 9;              // frag index = c*KN + s
    int s = fi % KN;
    int c = fi / KN;
    int k;
    if (layer == 0 || layer == 4)
        k = s * 32 + gg * 8 + e;                              // natural (build_frags0 input)
    else
        k = s * 32 + ((e >> 2) << 4) + (gg << 2) + (e & 3);   // tau (MFMA-output input)
    int col = (c << 4) + (lane & 15);
    float v = 0.f;
    if (layer < 8) {
        if (k < K_[layer]) v = pp.w[layer][k * NO_[layer] + col];
    } else {
        if ((lane & 15) == 0) v = pp.w[layer][k];   // k < 96 always
    }
    dst[OFF_[layer] + u] = f2b(v);
}

// Row softmax (in-place on the a-region in d_out) + fused agg[f] = sum_j p[j]*src[b,j,f]
template<int F>
__global__ __launch_bounds__(256)
void softmax_agg_kernel(float* __restrict__ amat, const float* __restrict__ src,
                        float* __restrict__ agg)
{
    __shared__ float pl[256];
    __shared__ float redm[4], reds[4];
    const int row = blockIdx.x;     // b*256 + i
    const int b = row >> 8;
    float* arow = amat + row * 256;
    const int t = threadIdx.x;
    const int lane = t & 63, wid = t >> 6;
    float v = arow[t];
    float m = v;
#pragma unroll
    for (int off = 32; off; off >>= 1) m = fmaxf(m, __shfl_xor(m, off));
    if (lane == 0) redm[wid] = m;
    __syncthreads();
    m = fmaxf(fmaxf(redm[0], redm[1]), fmaxf(redm[2], redm[3]));
    float e = __expf(v - m);
    float sum = e;
#pragma unroll
    for (int off = 32; off; off >>= 1) sum += __shfl_xor(sum, off);
    if (lane == 0) reds[wid] = sum;
    __syncthreads();
    sum = reds[0] + reds[1] + reds[2] + reds[3];
    float p = e / sum;
    arow[t] = p;
    pl[t] = p;
    __syncthreads();
    if (t < F) {
        const float* sb = src + (b * 256) * F + t;
        float acc = 0.f;
#pragma unroll 8
        for (int j = 0; j < 256; ++j)
            acc += pl[j] * sb[j * F];
        agg[row * F + t] = acc;
    }
}

// x1 = leaky([x | agg0] @ g0_w^T + g0_b); xc = [x | x1]
__global__ __launch_bounds__(64)
void graph0_kernel(const float* __restrict__ x, const float* __restrict__ agg0,
                   const float* __restrict__ w, const float* __restrict__ bias,
                   float* __restrict__ xc)
{
    int row = blockIdx.x;
    int t = threadIdx.x;
    const float* xr = x + row * 24;
    const float* ar = agg0 + row * 24;
    if (t < 24) xc[row * 72 + t] = xr[t];
    if (t < 48) {
        float acc = bias[t];
#pragma unroll
        for (int f = 0; f < 24; ++f) acc += xr[f] * w[t * 48 + f];
#pragma unroll
        for (int f = 0; f < 24; ++f) acc += ar[f] * w[t * 48 + 24 + f];
        acc = acc >= 0.f ? acc : 0.01f * acc;
        xc[row * 72 + 24 + t] = acc;
    }
}

// out = [xc | agg1] @ g1_w^T + g1_b   (no activation)
__global__ __launch_bounds__(64)
void graph1_kernel(const float* __restrict__ xc, const float* __restrict__ agg1,
                   const float* __restrict__ w, const float* __restrict__ bias,
                   float* __restrict__ out)
{
    int row = blockIdx.x;
    int t = threadIdx.x;
    float acc = 0.f;
    for (int idx = t; idx < 144; idx += 64) {
        float v = (idx < 72) ? xc[row * 72 + idx] : agg1[row * 72 + idx - 72];
        acc += v * w[idx];
    }
#pragma unroll
    for (int off = 32; off >= 1; off >>= 1) acc += __shfl_xor(acc, off);
    if (t == 0) out[row] = acc + bias[0];
}

extern "C" void kernel_launch(void* const* d_in, const int* in_sizes, int n_in,
                              void* d_out, int out_size, void* d_ws, size_t ws_size,
                              hipStream_t stream)
{
    const float* x = (const float*)d_in[0];
    float* out = (float*)d_out;
    float* a0 = out + 2048;
    float* a1 = a0 + 524288;

    char* ws = (char*)d_ws;
    unsigned short* packed = (unsigned short*)ws;          // 211968 bf16 = 423,936 B
    float* xc   = (float*)(ws + 458752);                   // [2048][72] f32
    float* agg0 = (float*)(ws + 1048576);                  // [2048][24] f32
    float* agg1 = (float*)(ws + 1245184);                  // [2048][72] f32

    PackPtrs pp;
    pp.w[0] = (const float*)d_in[1];   // a0_w0 [24,192]
    pp.w[1] = (const float*)d_in[3];   // a0_w1 [192,192]
    pp.w[2] = (const float*)d_in[5];   // a0_w2
    pp.w[3] = (const float*)d_in[7];   // a0_w3 [192,96]
    pp.w[4] = (const float*)d_in[11];  // a1_w0 [72,192]
    pp.w[5] = (const float*)d_in[13];  // a1_w1
    pp.w[6] = (const float*)d_in[15];  // a1_w2
    pp.w[7] = (const float*)d_in[17];  // a1_w3
    pp.w[8] = (const float*)d_in[9];   // a0_w4 [96,1]
    pp.w[9] = (const float*)d_in[19];  // a1_w4 [96,1]
    pack_kernel<<<828, 256, 0, stream>>>(pp, packed);      // 828*256 == 211968

    adj_mlp_kernel<24, 1><<<4096, 256, 0, stream>>>(
        x, packed, packed + 208896,
        (const float*)d_in[2], (const float*)d_in[4], (const float*)d_in[6],
        (const float*)d_in[8], (const float*)d_in[10], a0);

    softmax_agg_kernel<24><<<2048, 256, 0, stream>>>(a0, x, agg0);

    graph0_kernel<<<2048, 64, 0, stream>>>(x, agg0,
        (const float*)d_in[21], (const float*)d_in[22], xc);

    adj_mlp_kernel<72, 3><<<4096, 256, 0, stream>>>(
        xc, packed + 98304, packed + 210432,
        (const float*)d_in[12], (const float*)d_in[14], (const float*)d_in[16],
        (const float*)d_in[18], (const float*)d_in[20], a1);

    softmax_agg_kernel<72><<<2048, 256, 0, stream>>>(a1, xc, agg1);

    graph1_kernel<<<2048, 64, 0, stream>>>(xc, agg1,
        (const float*)d_in[23], (const float*)d_in[24], out);
}

// Round 2
// 251.185 us; speedup vs baseline: 1.2751x; 1.2068x over previous
//
#include <hip/hip_runtime.h>

typedef __bf16 bf16x8 __attribute__((ext_vector_type(8)));
typedef float f32x4 __attribute__((ext_vector_type(4)));

__device__ __forceinline__ unsigned short f2b(float f) {
    union { float f; unsigned u; } c; c.f = f;
    unsigned u = c.u;
    return (unsigned short)((u + 0x7FFFu + ((u >> 16) & 1u)) >> 16);
}

__device__ __forceinline__ unsigned pack2(float v0, float v1) {
    union { __bf16 h[2]; unsigned u; } c;
    c.h[0] = (__bf16)v0; c.h[1] = (__bf16)v1;
    return c.u;
}

// Direct global->LDS DMA, 16 B per lane. LDS dest is wave-uniform base + lane*16;
// global src is per-lane. Layout here is exactly that pattern (m97 structure).
__device__ __forceinline__ void gload_lds16(const unsigned short* g, unsigned short* l) {
    __builtin_amdgcn_global_load_lds(
        (__attribute__((address_space(1))) unsigned int*)(g),
        (__attribute__((address_space(3))) unsigned int*)(l), 16, 0, 0);
}

// Stage NLOADS x 1024B chunks of a packed weight layer into LDS, distributed
// round-robin over the block's 8 waves. idx is wave-uniform -> uniform LDS base.
template<int NLOADS>
__device__ __forceinline__ void stage_layer(const unsigned short* __restrict__ g,
                                            unsigned short* l, int wid, int lane)
{
#pragma unroll
    for (int k = 0; k < (NLOADS + 7) / 8; ++k) {
        const int idx = wid + k * 8;
        if ((NLOADS % 8 == 0) || idx < NLOADS)
            gload_lds16(g + idx * 512 + lane * 8, l + idx * 512);
    }
}

// Build layer-0 B-frags: B0[t][s] holds |x_i - x_j| transposed (k=fin, col=pos).
// Lane (cl,g): elem e = h0[pos=16t+cl][f=32s+8g+e]; frags fully valid or fully zero
// (CIN multiple of 8).
template<int CIN, int KN0>
__device__ __forceinline__ void build_frags0(const float* __restrict__ xi,
    const float* __restrict__ xj, int cl, int g, bf16x8 (&B0)[2][6])
{
#pragma unroll
    for (int s = 0; s < KN0; ++s) {
        const int f0 = s * 32 + 8 * g;
        const bool valid = f0 < CIN;
        f32x4 xa = {0.f,0.f,0.f,0.f}, xb = {0.f,0.f,0.f,0.f};
        if (valid) { xa = *(const f32x4*)(xi + f0); xb = *(const f32x4*)(xi + f0 + 4); }
#pragma unroll
        for (int t = 0; t < 2; ++t) {
            bf16x8 r;
            if (valid) {
                const float* pj = xj + (16 * t + cl) * CIN + f0;
                f32x4 ja = *(const f32x4*)pj, jb = *(const f32x4*)(pj + 4);
#pragma unroll
                for (int e = 0; e < 4; ++e) {
                    r[e]     = (__bf16)fabsf(xa[e] - ja[e]);
                    r[e + 4] = (__bf16)fabsf(xb[e] - jb[e]);
                }
            } else {
#pragma unroll
                for (int e = 0; e < 8; ++e) r[e] = (__bf16)0.f;
            }
            B0[t][s] = r;
        }
    }
}

// One F-mode layer, weights read from LDS (ds_read_b128, conflict-free lane*16
// pattern). Shuffle-free repack: next-layer frag s takes channels from acc tiles
// a=2s,2s+1 resident in the SAME lane; downstream weights are tau-permuted to match.
template<int KN, int CB>
__device__ __forceinline__ void run_layer(const unsigned short* wlds,
    const float* __restrict__ bias, const bf16x8 (&Bc)[2][6], bf16x8 (&Bn)[2][6],
    int lane, int g)
{
#pragma unroll
    for (int cp = 0; cp < CB / 2; ++cp) {
        f32x4 acc[2][2];                       // [cc][t]
#pragma unroll
        for (int cc = 0; cc < 2; ++cc) {
            f32x4 bv = *(const f32x4*)&bias[(2 * cp + cc) * 16 + 4 * g];
            acc[cc][0] = bv; acc[cc][1] = bv;
        }
#pragma unroll
        for (int s = 0; s < KN; ++s) {
#pragma unroll
            for (int cc = 0; cc < 2; ++cc) {
                bf16x8 w = *(const bf16x8*)&wlds[(((2 * cp + cc) * KN + s) * 64 + lane) * 8];
#pragma unroll
                for (int t = 0; t < 2; ++t)
                    acc[cc][t] = __builtin_amdgcn_mfma_f32_16x16x32_bf16(w, Bc[t][s], acc[cc][t], 0, 0, 0);
            }
        }
#pragma unroll
        for (int t = 0; t < 2; ++t) {
            union { unsigned w[4]; bf16x8 v; } outv;
#pragma unroll
            for (int cc = 0; cc < 2; ++cc)
#pragma unroll
                for (int m = 0; m < 2; ++m) {
                    float v0 = acc[cc][t][2 * m], v1 = acc[cc][t][2 * m + 1];
                    v0 = fmaxf(v0, 0.01f * v0);      // LeakyReLU(0.01)
                    v1 = fmaxf(v1, 0.01f * v1);
                    outv.w[cc * 2 + m] = pack2(v0, v1);
                }
            Bn[t][cp] = outv.v;
        }
    }
}

// Fused adjacency MLP. Block = 512 threads = 8 waves, all sharing one (b,i) row;
// wave owns 32 j's. Weights double-buffered in LDS (2 x 72 KiB), staged one layer
// ahead via global_load_lds -> 8x reduction in L2 weight traffic vs per-wave fetch.
template<int CIN, int KN0>
__global__ __launch_bounds__(512, 2)
void adj_mlp_kernel(const float* __restrict__ src,
                    const unsigned short* __restrict__ wchain,
                    const unsigned short* __restrict__ w4f,
                    const float* __restrict__ b0, const float* __restrict__ b1,
                    const float* __restrict__ b2, const float* __restrict__ b3,
                    const float* __restrict__ b4,
                    float* __restrict__ logits)
{
    __shared__ unsigned short wbuf[2][36864];   // 2 x 72 KiB: one full 192x192 layer each
    const int tid = threadIdx.x;
    const int wid = tid >> 6, lane = tid & 63;
    const int cl = lane & 15, g = lane >> 4;
    const int p0 = blockIdx.x * 256 + wid * 32;
    const int b = p0 >> 16, i = (p0 >> 8) & 255, j0 = p0 & 255;
    const float* xi = src + (b * 256 + i) * CIN;
    const float* xj = src + (b * 256 + j0) * CIN;

    // Prologue: stage L0, build input frags under the staging latency.
    stage_layer<12 * KN0>(wchain, wbuf[0], wid, lane);

    bf16x8 Ba[2][6], Bb[2][6];
    build_frags0<CIN, KN0>(xi, xj, cl, g, Ba);
    __syncthreads();                                     // L0 staged

    stage_layer<72>(wchain + 12 * KN0 * 512, wbuf[1], wid, lane);          // L1 ->
    run_layer<KN0, 12>(wbuf[0], b0, Ba, Bb, lane, g);
    __syncthreads();                                     // L1 staged, buf0 free

    stage_layer<72>(wchain + 12 * KN0 * 512 + 36864, wbuf[0], wid, lane);  // L2 ->
    run_layer<6, 12>(wbuf[1], b1, Bb, Ba, lane, g);
    __syncthreads();                                     // L2 staged, buf1 free

    stage_layer<36>(wchain + 12 * KN0 * 512 + 73728, wbuf[1], wid, lane);  // L3 ->
    run_layer<6, 12>(wbuf[0], b2, Ba, Bb, lane, g);
    __syncthreads();                                     // L3 staged

    run_layer<6, 6>(wbuf[1], b3, Bb, Ba, lane, g);       // 192 -> 96, frags in Ba[t][0..2]

    // final 96 -> 1: tiny w4 stays in global (L2-hit, 6 loads/wave)
    const float bv4 = b4[0];
#pragma unroll
    for (int t = 0; t < 2; ++t) {
        f32x4 acc = {bv4, bv4, bv4, bv4};
#pragma unroll
        for (int s = 0; s < 3; ++s) {
            bf16x8 w = *(const bf16x8*)(w4f + (s * 64 + lane) * 8);
            acc = __builtin_amdgcn_mfma_f32_16x16x32_bf16(w, Ba[t][s], acc, 0, 0, 0);
        }
        if (g == 0) {
            int j = j0 + 16 * t + cl;
            float lg = acc[0];
            if (j == i) lg -= 1e8f;
            logits[(b * 256 + i) * 256 + j] = lg;
        }
    }
}

// Pre-pack weight matrices (bf16). Same lane<->element map serves A- and B-frags.
// Layers 0-7: conv chains (a0 then a1). Layers 8-9: w4 vectors in row/col 0.
// Layers whose INPUT comes from a previous MFMA layer (1,2,3, 5,6,7, 8,9) use the
// shuffle-free k-permutation tau(s,g,e) = 32s + 16*(e>>2) + 4g + (e&3); layers fed
// by build_frags0 (0, 4) keep the natural order k = 32s + 8g + e.
struct PackPtrs { const float* w[10]; };

__global__ void pack_kernel(PackPtrs pp, unsigned short* __restrict__ dst)
{
    const int K_[10]   = {24, 192, 192, 192, 72, 192, 192, 192, 96, 96};
    const int KN_[10]  = {1, 6, 6, 6, 3, 6, 6, 6, 3, 3};
    const int NO_[10]  = {192, 192, 192, 96, 192, 192, 192, 96, 1, 1};
    const int OFF_[10] = {0, 6144, 43008, 79872, 98304, 116736, 153600, 190464, 208896, 210432};
    const int LEN_[10] = {6144, 36864, 36864, 18432, 18432, 36864, 36864, 18432, 1536, 1536};
    int t = blockIdx.x * 256 + threadIdx.x;   // total threads == 211968 exactly
    int layer = 0, base = 0;
#pragma unroll
    for (int L = 0; L < 10; ++L)
        if (t >= base + LEN_[L]) { base += LEN_[L]; layer = L + 1; }
    if (layer >= 10) return;
    int u = t - base;
    int e = u & 7;
    int lane = (u >> 3) & 63;
    int gg = lane >> 4;
    int KN = KN_[layer];
    int fi = u >> 9;              // frag index = c*KN + s
    int s = fi % KN;
    int c = fi / KN;
    int k;
    if (layer == 0 || layer == 4)
        k = s * 32 + gg * 8 + e;                              // natural (build_frags0 input)
    else
        k = s * 32 + ((e >> 2) << 4) + (gg << 2) + (e & 3);   // tau (MFMA-output input)
    int col = (c << 4) + (lane & 15);
    float v = 0.f;
    if (layer < 8) {
        if (k < K_[layer]) v = pp.w[layer][k * NO_[layer] + col];
    } else {
        if ((lane & 15) == 0) v = pp.w[layer][k];   // k < 96 always
    }
    dst[OFF_[layer] + u] = f2b(v);
}

// Row softmax (in-place on the a-region in d_out) + fused agg[f] = sum_j p[j]*src[b,j,f]
template<int F>
__global__ __launch_bounds__(256)
void softmax_agg_kernel(float* __restrict__ amat, const float* __restrict__ src,
                        float* __restrict__ agg)
{
    __shared__ float pl[256];
    __shared__ float redm[4], reds[4];
    const int row = blockIdx.x;     // b*256 + i
    const int b = row >> 8;
    float* arow = amat + row * 256;
    const int t = threadIdx.x;
    const int lane = t & 63, wid = t >> 6;
    float v = arow[t];
    float m = v;
#pragma unroll
    for (int off = 32; off; off >>= 1) m = fmaxf(m, __shfl_xor(m, off));
    if (lane == 0) redm[wid] = m;
    __syncthreads();
    m = fmaxf(fmaxf(redm[0], redm[1]), fmaxf(redm[2], redm[3]));
    float e = __expf(v - m);
    float sum = e;
#pragma unroll
    for (int off = 32; off; off >>= 1) sum += __shfl_xor(sum, off);
    if (lane == 0) reds[wid] = sum;
    __syncthreads();
    sum = reds[0] + reds[1] + reds[2] + reds[3];
    float p = e / sum;
    arow[t] = p;
    pl[t] = p;
    __syncthreads();
    if (t < F) {
        const float* sb = src + (b * 256) * F + t;
        float acc = 0.f;
#pragma unroll 8
        for (int j = 0; j < 256; ++j)
            acc += pl[j] * sb[j * F];
        agg[row * F + t] = acc;
    }
}

// x1 = leaky([x | agg0] @ g0_w^T + g0_b); xc = [x | x1]
__global__ __launch_bounds__(64)
void graph0_kernel(const float* __restrict__ x, const float* __restrict__ agg0,
                   const float* __restrict__ w, const float* __restrict__ bias,
                   float* __restrict__ xc)
{
    int row = blockIdx.x;
    int t = threadIdx.x;
    const float* xr = x + row * 24;
    const float* ar = agg0 + row * 24;
    if (t < 24) xc[row * 72 + t] = xr[t];
    if (t < 48) {
        float acc = bias[t];
#pragma unroll
        for (int f = 0; f < 24; ++f) acc += xr[f] * w[t * 48 + f];
#pragma unroll
        for (int f = 0; f < 24; ++f) acc += ar[f] * w[t * 48 + 24 + f];
        acc = acc >= 0.f ? acc : 0.01f * acc;
        xc[row * 72 + 24 + t] = acc;
    }
}

// out = [xc | agg1] @ g1_w^T + g1_b   (no activation)
__global__ __launch_bounds__(64)
void graph1_kernel(const float* __restrict__ xc, const float* __restrict__ agg1,
                   const float* __restrict__ w, const float* __restrict__ bias,
                   float* __restrict__ out)
{
    int row = blockIdx.x;
    int t = threadIdx.x;
    float acc = 0.f;
    for (int idx = t; idx < 144; idx += 64) {
        float v = (idx < 72) ? xc[row * 72 + idx] : agg1[row * 72 + idx - 72];
        acc += v * w[idx];
    }
#pragma unroll
    for (int off = 32; off >= 1; off >>= 1) acc += __shfl_xor(acc, off);
    if (t == 0) out[row] = acc + bias[0];
}

extern "C" void kernel_launch(void* const* d_in, const int* in_sizes, int n_in,
                              void* d_out, int out_size, void* d_ws, size_t ws_size,
                              hipStream_t stream)
{
    const float* x = (const float*)d_in[0];
    float* out = (float*)d_out;
    float* a0 = out + 2048;
    float* a1 = a0 + 524288;

    char* ws = (char*)d_ws;
    unsigned short* packed = (unsigned short*)ws;          // 211968 bf16 = 423,936 B
    float* xc   = (float*)(ws + 458752);                   // [2048][72] f32
    float* agg0 = (float*)(ws + 1048576);                  // [2048][24] f32
    float* agg1 = (float*)(ws + 1245184);                  // [2048][72] f32

    PackPtrs pp;
    pp.w[0] = (const float*)d_in[1];   // a0_w0 [24,192]
    pp.w[1] = (const float*)d_in[3];   // a0_w1 [192,192]
    pp.w[2] = (const float*)d_in[5];   // a0_w2
    pp.w[3] = (const float*)d_in[7];   // a0_w3 [192,96]
    pp.w[4] = (const float*)d_in[11];  // a1_w0 [72,192]
    pp.w[5] = (const float*)d_in[13];  // a1_w1
    pp.w[6] = (const float*)d_in[15];  // a1_w2
    pp.w[7] = (const float*)d_in[17];  // a1_w3
    pp.w[8] = (const float*)d_in[9];   // a0_w4 [96,1]
    pp.w[9] = (const float*)d_in[19];  // a1_w4 [96,1]
    pack_kernel<<<828, 256, 0, stream>>>(pp, packed);      // 828*256 == 211968

    adj_mlp_kernel<24, 1><<<2048, 512, 0, stream>>>(
        x, packed, packed + 208896,
        (const float*)d_in[2], (const float*)d_in[4], (const float*)d_in[6],
        (const float*)d_in[8], (const float*)d_in[10], a0);

    softmax_agg_kernel<24><<<2048, 256, 0, stream>>>(a0, x, agg0);

    graph0_kernel<<<2048, 64, 0, stream>>>(x, agg0,
        (const float*)d_in[21], (const float*)d_in[22], xc);

    adj_mlp_kernel<72, 3><<<2048, 512, 0, stream>>>(
        xc, packed + 98304, packed + 210432,
        (const float*)d_in[12], (const float*)d_in[14], (const float*)d_in[16],
        (const float*)d_in[18], (const float*)d_in[20], a1);

    softmax_agg_kernel<72><<<2048, 256, 0, stream>>>(a1, xc, agg1);

    graph1_kernel<<<2048, 64, 0, stream>>>(xc, agg1,
        (const float*)d_in[23], (const float*)d_in[24], out);
}

// Round 3
// 173.549 us; speedup vs baseline: 1.8454x; 1.4473x over previous
//
#include <hip/hip_runtime.h>

typedef __bf16 bf16x8 __attribute__((ext_vector_type(8)));
typedef float f32x4 __attribute__((ext_vector_type(4)));

__device__ __forceinline__ unsigned short f2b(float f) {
    union { float f; unsigned u; } c; c.f = f;
    unsigned u = c.u;
    return (unsigned short)((u + 0x7FFFu + ((u >> 16) & 1u)) >> 16);
}

__device__ __forceinline__ unsigned pack2(float v0, float v1) {
    union { __bf16 h[2]; unsigned u; } c;
    c.h[0] = (__bf16)v0; c.h[1] = (__bf16)v1;
    return c.u;
}

// Direct global->LDS DMA, 16 B per lane. LDS dest is wave-uniform base + lane*16;
// global src is per-lane. Layout here is exactly that pattern (m97 structure).
__device__ __forceinline__ void gload_lds16(const unsigned short* g, unsigned short* l) {
    __builtin_amdgcn_global_load_lds(
        (__attribute__((address_space(1))) unsigned int*)(g),
        (__attribute__((address_space(3))) unsigned int*)(l), 16, 0, 0);
}

// Stage NLOADS x 1024B chunks of a packed weight layer into LDS, distributed
// round-robin over the block's 8 waves. idx is wave-uniform -> uniform LDS base.
template<int NLOADS>
__device__ __forceinline__ void stage_layer(const unsigned short* __restrict__ g,
                                            unsigned short* l, int wid, int lane)
{
#pragma unroll
    for (int k = 0; k < (NLOADS + 7) / 8; ++k) {
        const int idx = wid + k * 8;
        if ((NLOADS % 8 == 0) || idx < NLOADS)
            gload_lds16(g + idx * 512 + lane * 8, l + idx * 512);
    }
}

// Build layer-0 B-frags: B0[t][s] holds |x_i - x_j| transposed (k=fin, col=pos).
// Lane (cl,g): elem e = h0[pos=16t+cl][f=32s+8g+e]; frags fully valid or fully zero
// (CIN multiple of 8).
template<int CIN, int KN0>
__device__ __forceinline__ void build_frags0(const float* __restrict__ xi,
    const float* __restrict__ xj, int cl, int g, bf16x8 (&B0)[2][6])
{
#pragma unroll
    for (int s = 0; s < KN0; ++s) {
        const int f0 = s * 32 + 8 * g;
        const bool valid = f0 < CIN;
        f32x4 xa = {0.f,0.f,0.f,0.f}, xb = {0.f,0.f,0.f,0.f};
        if (valid) { xa = *(const f32x4*)(xi + f0); xb = *(const f32x4*)(xi + f0 + 4); }
#pragma unroll
        for (int t = 0; t < 2; ++t) {
            bf16x8 r;
            if (valid) {
                const float* pj = xj + (16 * t + cl) * CIN + f0;
                f32x4 ja = *(const f32x4*)pj, jb = *(const f32x4*)(pj + 4);
#pragma unroll
                for (int e = 0; e < 4; ++e) {
                    r[e]     = (__bf16)fabsf(xa[e] - ja[e]);
                    r[e + 4] = (__bf16)fabsf(xb[e] - jb[e]);
                }
            } else {
#pragma unroll
                for (int e = 0; e < 8; ++e) r[e] = (__bf16)0.f;
            }
            B0[t][s] = r;
        }
    }
}

// One F-mode layer, weights read from LDS (ds_read_b128, conflict-free lane*16
// pattern). Shuffle-free repack: next-layer frag s takes channels from acc tiles
// a=2s,2s+1 resident in the SAME lane; downstream weights are tau-permuted to match.
template<int KN, int CB>
__device__ __forceinline__ void run_layer(const unsigned short* wlds,
    const float* __restrict__ bias, const bf16x8 (&Bc)[2][6], bf16x8 (&Bn)[2][6],
    int lane, int g)
{
#pragma unroll
    for (int cp = 0; cp < CB / 2; ++cp) {
        f32x4 acc[2][2];                       // [cc][t]
#pragma unroll
        for (int cc = 0; cc < 2; ++cc) {
            f32x4 bv = *(const f32x4*)&bias[(2 * cp + cc) * 16 + 4 * g];
            acc[cc][0] = bv; acc[cc][1] = bv;
        }
#pragma unroll
        for (int s = 0; s < KN; ++s) {
#pragma unroll
            for (int cc = 0; cc < 2; ++cc) {
                bf16x8 w = *(const bf16x8*)&wlds[(((2 * cp + cc) * KN + s) * 64 + lane) * 8];
#pragma unroll
                for (int t = 0; t < 2; ++t)
                    acc[cc][t] = __builtin_amdgcn_mfma_f32_16x16x32_bf16(w, Bc[t][s], acc[cc][t], 0, 0, 0);
            }
        }
#pragma unroll
        for (int t = 0; t < 2; ++t) {
            union { unsigned w[4]; bf16x8 v; } outv;
#pragma unroll
            for (int cc = 0; cc < 2; ++cc)
#pragma unroll
                for (int m = 0; m < 2; ++m) {
                    float v0 = acc[cc][t][2 * m], v1 = acc[cc][t][2 * m + 1];
                    v0 = fmaxf(v0, 0.01f * v0);      // LeakyReLU(0.01)
                    v1 = fmaxf(v1, 0.01f * v1);
                    outv.w[cc * 2 + m] = pack2(v0, v1);
                }
            Bn[t][cp] = outv.v;
        }
    }
}

// Fused adjacency MLP exploiting logit symmetry: h(i,j) = MLP(|x_i-x_j|) ==
// h(j,i), so only upper-triangle 32x32 j-tiles are computed; off-diagonal tiles
// mirror-write logits[j][i]. Per batch: 36 tile-pairs x 32 rows = 1152 wave-units
// (56% of full). Block = 512 threads = 8 waves; waves share only the staged
// weights (double-buffered 2 x 72 KiB LDS, global_load_lds one layer ahead).
template<int CIN, int KN0>
__global__ __launch_bounds__(512, 2)
void adj_mlp_kernel(const float* __restrict__ src,
                    const unsigned short* __restrict__ wchain,
                    const unsigned short* __restrict__ w4f,
                    const float* __restrict__ b0, const float* __restrict__ b1,
                    const float* __restrict__ b2, const float* __restrict__ b3,
                    const float* __restrict__ b4,
                    float* __restrict__ logits)
{
    __shared__ unsigned short wbuf[2][36864];   // 2 x 72 KiB: one full 192x192 layer each
    const int tid = threadIdx.x;
    const int wid = tid >> 6, lane = tid & 63;
    const int cl = lane & 15, g = lane >> 4;

    // Triangular wave-unit decode: u -> (b, i, j0) with j0/32 >= i/32.
    const int u = blockIdx.x * 8 + wid;         // 0..9215
    const int b = u / 1152;
    const int r = u - b * 1152;
    const int tp = r >> 5;                      // tile-pair 0..35 (upper tri of 8x8)
    const int row_in = r & 31;
    int rg = 0, tt = tp;
#pragma unroll 8
    for (;;) { int cnt = 8 - rg; if (tt < cnt) break; tt -= cnt; ++rg; }
    const int cg = rg + tt;
    const int i = rg * 32 + row_in;
    const int j0 = cg * 32;
    const bool offdiag = (cg != rg);

    const float* xi = src + (b * 256 + i) * CIN;
    const float* xj = src + (b * 256 + j0) * CIN;

    // Prologue: stage L0, build input frags under the staging latency.
    stage_layer<12 * KN0>(wchain, wbuf[0], wid, lane);

    bf16x8 Ba[2][6], Bb[2][6];
    build_frags0<CIN, KN0>(xi, xj, cl, g, Ba);
    __syncthreads();                                     // L0 staged

    stage_layer<72>(wchain + 12 * KN0 * 512, wbuf[1], wid, lane);          // L1 ->
    run_layer<KN0, 12>(wbuf[0], b0, Ba, Bb, lane, g);
    __syncthreads();                                     // L1 staged, buf0 free

    stage_layer<72>(wchain + 12 * KN0 * 512 + 36864, wbuf[0], wid, lane);  // L2 ->
    run_layer<6, 12>(wbuf[1], b1, Bb, Ba, lane, g);
    __syncthreads();                                     // L2 staged, buf1 free

    stage_layer<36>(wchain + 12 * KN0 * 512 + 73728, wbuf[1], wid, lane);  // L3 ->
    run_layer<6, 12>(wbuf[0], b2, Ba, Bb, lane, g);
    __syncthreads();                                     // L3 staged

    run_layer<6, 6>(wbuf[1], b3, Bb, Ba, lane, g);       // 192 -> 96, frags in Ba[t][0..2]

    // final 96 -> 1: tiny w4 stays in global (L2-hit, 6 loads/wave)
    const float bv4 = b4[0];
#pragma unroll
    for (int t = 0; t < 2; ++t) {
        f32x4 acc = {bv4, bv4, bv4, bv4};
#pragma unroll
        for (int s = 0; s < 3; ++s) {
            bf16x8 w = *(const bf16x8*)(w4f + (s * 64 + lane) * 8);
            acc = __builtin_amdgcn_mfma_f32_16x16x32_bf16(w, Ba[t][s], acc, 0, 0, 0);
        }
        if (g == 0) {
            int j = j0 + 16 * t + cl;
            float lg = acc[0];
            if (j == i) lg -= 1e8f;
            logits[(b * 256 + i) * 256 + j] = lg;
            if (offdiag)
                logits[(b * 256 + j) * 256 + i] = lg;    // symmetric mirror (i != j)
        }
    }
}

// Pre-pack weight matrices (bf16). Same lane<->element map serves A- and B-frags.
// Layers 0-7: conv chains (a0 then a1). Layers 8-9: w4 vectors in row/col 0.
// Layers whose INPUT comes from a previous MFMA layer (1,2,3, 5,6,7, 8,9) use the
// shuffle-free k-permutation tau(s,g,e) = 32s + 16*(e>>2) + 4g + (e&3); layers fed
// by build_frags0 (0, 4) keep the natural order k = 32s + 8g + e.
struct PackPtrs { const float* w[10]; };

__global__ void pack_kernel(PackPtrs pp, unsigned short* __restrict__ dst)
{
    const int K_[10]   = {24, 192, 192, 192, 72, 192, 192, 192, 96, 96};
    const int KN_[10]  = {1, 6, 6, 6, 3, 6, 6, 6, 3, 3};
    const int NO_[10]  = {192, 192, 192, 96, 192, 192, 192, 96, 1, 1};
    const int OFF_[10] = {0, 6144, 43008, 79872, 98304, 116736, 153600, 190464, 208896, 210432};
    const int LEN_[10] = {6144, 36864, 36864, 18432, 18432, 36864, 36864, 18432, 1536, 1536};
    int t = blockIdx.x * 256 + threadIdx.x;   // total threads == 211968 exactly
    int layer = 0, base = 0;
#pragma unroll
    for (int L = 0; L < 10; ++L)
        if (t >= base + LEN_[L]) { base += LEN_[L]; layer = L + 1; }
    if (layer >= 10) return;
    int u = t - base;
    int e = u & 7;
    int lane = (u >> 3) & 63;
    int gg = lane >> 4;
    int KN = KN_[layer];
    int fi = u >> 9;              // frag index = c*KN + s
    int s = fi % KN;
    int c = fi / KN;
    int k;
    if (layer == 0 || layer == 4)
        k = s * 32 + gg * 8 + e;                              // natural (build_frags0 input)
    else
        k = s * 32 + ((e >> 2) << 4) + (gg << 2) + (e & 3);   // tau (MFMA-output input)
    int col = (c << 4) + (lane & 15);
    float v = 0.f;
    if (layer < 8) {
        if (k < K_[layer]) v = pp.w[layer][k * NO_[layer] + col];
    } else {
        if ((lane & 15) == 0) v = pp.w[layer][k];   // k < 96 always
    }
    dst[OFF_[layer] + u] = f2b(v);
}

// Row softmax (in-place on the a-region in d_out) + fused agg[f] = sum_j p[j]*src[b,j,f]
template<int F>
__global__ __launch_bounds__(256)
void softmax_agg_kernel(float* __restrict__ amat, const float* __restrict__ src,
                        float* __restrict__ agg)
{
    __shared__ float pl[256];
    __shared__ float redm[4], reds[4];
    const int row = blockIdx.x;     // b*256 + i
    const int b = row >> 8;
    float* arow = amat + row * 256;
    const int t = threadIdx.x;
    const int lane = t & 63, wid = t >> 6;
    float v = arow[t];
    float m = v;
#pragma unroll
    for (int off = 32; off; off >>= 1) m = fmaxf(m, __shfl_xor(m, off));
    if (lane == 0) redm[wid] = m;
    __syncthreads();
    m = fmaxf(fmaxf(redm[0], redm[1]), fmaxf(redm[2], redm[3]));
    float e = __expf(v - m);
    float sum = e;
#pragma unroll
    for (int off = 32; off; off >>= 1) sum += __shfl_xor(sum, off);
    if (lane == 0) reds[wid] = sum;
    __syncthreads();
    sum = reds[0] + reds[1] + reds[2] + reds[3];
    float p = e / sum;
    arow[t] = p;
    pl[t] = p;
    __syncthreads();
    if (t < F) {
        const float* sb = src + (b * 256) * F + t;
        float acc = 0.f;
#pragma unroll 8
        for (int j = 0; j < 256; ++j)
            acc += pl[j] * sb[j * F];
        agg[row * F + t] = acc;
    }
}

// x1 = leaky([x | agg0] @ g0_w^T + g0_b); xc = [x | x1]
__global__ __launch_bounds__(64)
void graph0_kernel(const float* __restrict__ x, const float* __restrict__ agg0,
                   const float* __restrict__ w, const float* __restrict__ bias,
                   float* __restrict__ xc)
{
    int row = blockIdx.x;
    int t = threadIdx.x;
    const float* xr = x + row * 24;
    const float* ar = agg0 + row * 24;
    if (t < 24) xc[row * 72 + t] = xr[t];
    if (t < 48) {
        float acc = bias[t];
#pragma unroll
        for (int f = 0; f < 24; ++f) acc += xr[f] * w[t * 48 + f];
#pragma unroll
        for (int f = 0; f < 24; ++f) acc += ar[f] * w[t * 48 + 24 + f];
        acc = acc >= 0.f ? acc : 0.01f * acc;
        xc[row * 72 + 24 + t] = acc;
    }
}

// out = [xc | agg1] @ g1_w^T + g1_b   (no activation)
__global__ __launch_bounds__(64)
void graph1_kernel(const float* __restrict__ xc, const float* __restrict__ agg1,
                   const float* __restrict__ w, const float* __restrict__ bias,
                   float* __restrict__ out)
{
    int row = blockIdx.x;
    int t = threadIdx.x;
    float acc = 0.f;
    for (int idx = t; idx < 144; idx += 64) {
        float v = (idx < 72) ? xc[row * 72 + idx] : agg1[row * 72 + idx - 72];
        acc += v * w[idx];
    }
#pragma unroll
    for (int off = 32; off >= 1; off >>= 1) acc += __shfl_xor(acc, off);
    if (t == 0) out[row] = acc + bias[0];
}

extern "C" void kernel_launch(void* const* d_in, const int* in_sizes, int n_in,
                              void* d_out, int out_size, void* d_ws, size_t ws_size,
                              hipStream_t stream)
{
    const float* x = (const float*)d_in[0];
    float* out = (float*)d_out;
    float* a0 = out + 2048;
    float* a1 = a0 + 524288;

    char* ws = (char*)d_ws;
    unsigned short* packed = (unsigned short*)ws;          // 211968 bf16 = 423,936 B
    float* xc   = (float*)(ws + 458752);                   // [2048][72] f32
    float* agg0 = (float*)(ws + 1048576);                  // [2048][24] f32
    float* agg1 = (float*)(ws + 1245184);                  // [2048][72] f32

    PackPtrs pp;
    pp.w[0] = (const float*)d_in[1];   // a0_w0 [24,192]
    pp.w[1] = (const float*)d_in[3];   // a0_w1 [192,192]
    pp.w[2] = (const float*)d_in[5];   // a0_w2
    pp.w[3] = (const float*)d_in[7];   // a0_w3 [192,96]
    pp.w[4] = (const float*)d_in[11];  // a1_w0 [72,192]
    pp.w[5] = (const float*)d_in[13];  // a1_w1
    pp.w[6] = (const float*)d_in[15];  // a1_w2
    pp.w[7] = (const float*)d_in[17];  // a1_w3
    pp.w[8] = (const float*)d_in[9];   // a0_w4 [96,1]
    pp.w[9] = (const float*)d_in[19];  // a1_w4 [96,1]
    pack_kernel<<<828, 256, 0, stream>>>(pp, packed);      // 828*256 == 211968

    adj_mlp_kernel<24, 1><<<1152, 512, 0, stream>>>(
        x, packed, packed + 208896,
        (const float*)d_in[2], (const float*)d_in[4], (const float*)d_in[6],
        (const float*)d_in[8], (const float*)d_in[10], a0);

    softmax_agg_kernel<24><<<2048, 256, 0, stream>>>(a0, x, agg0);

    graph0_kernel<<<2048, 64, 0, stream>>>(x, agg0,
        (const float*)d_in[21], (const float*)d_in[22], xc);

    adj_mlp_kernel<72, 3><<<1152, 512, 0, stream>>>(
        xc, packed + 98304, packed + 210432,
        (const float*)d_in[12], (const float*)d_in[14], (const float*)d_in[16],
        (const float*)d_in[18], (const float*)d_in[20], a1);

    softmax_agg_kernel<72><<<2048, 256, 0, stream>>>(a1, xc, agg1);

    graph1_kernel<<<2048, 64, 0, stream>>>(xc, agg1,
        (const float*)d_in[23], (const float*)d_in[24], out);
}